// Round 10
// baseline (130.473 us; speedup 1.0000x reference)
//
#include <hip/hip_runtime.h>
#include <hip/hip_bf16.h>
#include <math.h>

#define KNBR 20
#define NFK 384
#define NFPAD 392     // bf16 pad -> row stride 784B
#define CATPAD 264
#define KS1 12        // 384/32 k-steps
#define KS2 8         // 256/32 k-steps ("ones" block folded into bias2_eff)
#define WF1_PER_LAYER (8 * KS1 * 64 * 8)   // 49152
#define WF2_PER_LAYER (8 * KS2 * 64 * 8)   // 32768
#define INV2PI 0.15915494309189535f
#define NMEM_ELEMS 12800000                // 100000*128

typedef __attribute__((ext_vector_type(8))) short short8;
typedef __attribute__((ext_vector_type(4))) float f32x4;
typedef __attribute__((ext_vector_type(2))) float f32x2;
typedef __attribute__((ext_vector_type(4))) unsigned short u16x4;
typedef __attribute__((ext_vector_type(2))) unsigned short u16x2;

__device__ __forceinline__ unsigned short f2bf(float f) {
    unsigned u = __float_as_uint(f);
    unsigned r = (u + 0x7FFFu + ((u >> 16) & 1u)) >> 16;  // RNE
    return (unsigned short)r;
}
__device__ __forceinline__ float bf2f(unsigned short u) {
    return __uint_as_float((unsigned)u << 16);
}
__device__ __forceinline__ float fract_(float x) {
#if __has_builtin(__builtin_amdgcn_fractf)
    return __builtin_amdgcn_fractf(x);
#else
    return x - floorf(x);
#endif
}
__device__ __forceinline__ float cos_rev(float rev) {  // cos(2*pi*rev)
#if __has_builtin(__builtin_amdgcn_cosf)
    return __builtin_amdgcn_cosf(fract_(rev));
#else
    float o, r = fract_(rev);
    asm("v_cos_f32 %0, %1" : "=v"(o) : "v"(r));
    return o;
#endif
}
__device__ __forceinline__ f32x4 ldnt4(const float* p) {  // non-temporal 16B load
    return __builtin_nontemporal_load(reinterpret_cast<const f32x4*>(p));
}

// ---------------------------------------------------------------------------
// One-time setup: weight repack to MFMA B-frag order (bf16), ones-bias fold,
// memory-table f32 -> bf16 conversion PRESCALED x2 (node_feat = 2*memory).
// Conversion: nt READ (read-once), REGULAR store (keep memb cache-resident).
// Consumer reads: wf[(((ct*KS + ks)*64 + lane)*8 + j]
//   k = ks*32 + (lane>>4)*8 + j, col = ct*16 + (lane&15)
// ---------------------------------------------------------------------------
__global__ __launch_bounds__(256) void setup_kernel(
    const float* __restrict__ memory,
    const float* __restrict__ W1, const float* __restrict__ W2,
    const float* __restrict__ b2, const float* __restrict__ time_b,
    unsigned short* __restrict__ wf1, unsigned short* __restrict__ wf2,
    float* __restrict__ bias2_eff, unsigned short* __restrict__ memb)
{
    const int id = blockIdx.x * 256 + threadIdx.x;
    const int N1 = 2 * WF1_PER_LAYER;
    const int N2 = 2 * WF2_PER_LAYER;
    if (id < N1) {
        const int layer = id / WF1_PER_LAYER;
        const int idl = id % WF1_PER_LAYER;
        const int ct = idl / (KS1 * 512);
        const int ks = (idl / 512) % KS1;
        const int l = (idl >> 3) & 63;
        const int j = idl & 7;
        const int k = ks * 32 + (l >> 4) * 8 + j;
        const int col = ct * 16 + (l & 15);
        wf1[id] = f2bf(W1[(size_t)layer * NFK * 128 + k * 128 + col]);
    } else if (id < N1 + N2) {
        const int id2 = id - N1;
        const int layer = id2 / WF2_PER_LAYER;
        const int idl = id2 % WF2_PER_LAYER;
        const int ct = idl / (KS2 * 512);
        const int ks = (idl / 512) % KS2;
        const int l = (idl >> 3) & 63;
        const int j = idl & 7;
        const int k = ks * 32 + (l >> 4) * 8 + j;
        const int col = ct * 16 + (l & 15);
        wf2[id2] = f2bf(W2[(size_t)layer * NFK * 128 + k * 128 + col]);
    } else if (id < N1 + N2 + 256) {
        const int id3 = id - N1 - N2;
        const int layer = id3 / 128, col = id3 % 128;
        float s = b2[layer * 128 + col];
        for (int f = 0; f < 128; ++f)
            s += cosf(time_b[f]) * W2[(size_t)layer * NFK * 128 + (256 + f) * 128 + col];
        bias2_eff[id3] = s;
    } else {
        // prescaled x2 conversion (exact: 2*bf16(v) == bf16(2v))
        const size_t cid = (size_t)(id - (N1 + N2 + 256)) * 4;
        const f32x4 v = __builtin_nontemporal_load(
            reinterpret_cast<const f32x4*>(&memory[cid]));
        u16x4 o = { f2bf(2.f*v.x), f2bf(2.f*v.y), f2bf(2.f*v.z), f2bf(2.f*v.w) };
        *reinterpret_cast<u16x4*>(&memb[cid]) = o;   // cacheable store
    }
}

// ---------------------------------------------------------------------------
// Layer-1 fused MLP: 256 threads (4 waves), 16 rows/block.
// __launch_bounds__(256,4): cap VGPR at 128 -> 4 waves/SIMD (16 waves/CU)
// instead of the 2 waves/SIMD a >128-VGPR fully-unrolled loop would give.
// k-loop unroll capped at 10 to fit the 128-VGPR budget without spills.
// Staging: half-wave hw (32 lanes) owns 2 rows; 4 dims/lane.
// memb gathers: bf16 8B/lane, cacheable. edge gathers: f32 16B/lane, nt.
// Writes f32 cos/edge sums for rows<1024 into cache (reused by layer-2).
// ---------------------------------------------------------------------------
__global__ __launch_bounds__(256, 4) void mlp_l1(
    const unsigned short* __restrict__ memb,   // bf16 [100000,128], prescaled x2
    const float* __restrict__ edge_features,
    const float* __restrict__ timestamps,
    const float* __restrict__ time_w,
    const float* __restrict__ time_b,
    const int* __restrict__ source_nodes,
    const int* __restrict__ nbr1, const int* __restrict__ eidx1, const float* __restrict__ etime1,
    const int* __restrict__ nbr2, const int* __restrict__ eidx2, const float* __restrict__ etime2,
    const unsigned short* __restrict__ wf1,
    const unsigned short* __restrict__ wf2,
    const float* __restrict__ b1l,
    const float* __restrict__ bias2l,
    float* __restrict__ cache,                 // f32 [1024,256]: [cos_sum | edge_sum]
    unsigned short* __restrict__ emb_all)      // bf16 [21504,128] out
{
    __shared__ alignas(16) unsigned short nf[16][NFPAD];
    __shared__ alignas(16) unsigned short cat[16][CATPAD];
    __shared__ int   s_nbr[16][KNBR];
    __shared__ int   s_eix[16][KNBR];
    __shared__ float s_etm[16][KNBR];
    __shared__ float s_ts[16];
    __shared__ int   s_mid[16];

    const int tid = threadIdx.x;
    const int row0 = blockIdx.x * 16;
    const int l32 = tid & 31;
    const int d4 = l32 * 4;
    const int hw = tid >> 5;

    // --- block-cooperative index staging ---
    const int* nbr_src; const int* eix_src; const float* etm_src;
    if (row0 < 1024) {
        nbr_src = nbr1 + row0 * KNBR; eix_src = eidx1 + row0 * KNBR; etm_src = etime1 + row0 * KNBR;
    } else {
        const int i0 = row0 - 1024;
        nbr_src = nbr2 + i0 * KNBR; eix_src = eidx2 + i0 * KNBR; etm_src = etime2 + i0 * KNBR;
    }
    for (int i = tid; i < 16 * KNBR; i += 256) {
        (&s_nbr[0][0])[i] = nbr_src[i];
        (&s_eix[0][0])[i] = eix_src[i];
        (&s_etm[0][0])[i] = etm_src[i];
    }
    if (tid < 16) {
        const int row = row0 + tid;
        float ts; int mid;
        if (row0 < 1024) { ts = timestamps[row]; mid = source_nodes[row]; }
        else { const int i = row - 1024; ts = timestamps[i / KNBR]; mid = nbr1[i]; }
        s_ts[tid] = ts;
        s_mid[tid] = mid;
    }
    __syncthreads();

    const f32x4 twv = *reinterpret_cast<const f32x4*>(&time_w[d4]);
    const f32x4 tbv = *reinterpret_cast<const f32x4*>(&time_b[d4]);
    const f32x4 wtr = twv * INV2PI;
    const f32x4 btr = tbv * INV2PI;
    const bool wcache = (row0 < 1024);

#pragma unroll
    for (int ri = 0; ri < 2; ++ri) {
        const int r = hw * 2 + ri;
        const float ts = s_ts[r];
        f32x4 am = {0,0,0,0}, ac = {0,0,0,0}, ae = {0,0,0,0};
#pragma unroll 10
        for (int k = 0; k < KNBR; ++k) {
            const int nid = s_nbr[r][k];
            const int eid = s_eix[r][k];
            const float dt = ts - s_etm[r][k];
            const float live = (nid != 0) ? 1.f : 0.f;
            const u16x4 mu = *reinterpret_cast<const u16x4*>(&memb[(size_t)nid * 128 + d4]);
            const f32x4 ev = ldnt4(&edge_features[(size_t)eid * 128 + d4]);
            am.x += live * bf2f(mu.x); am.y += live * bf2f(mu.y);
            am.z += live * bf2f(mu.z); am.w += live * bf2f(mu.w);
            ae += live * ev;
            ac.x += live * cos_rev(fmaf(dt, wtr.x, btr.x));
            ac.y += live * cos_rev(fmaf(dt, wtr.y, btr.y));
            ac.z += live * cos_rev(fmaf(dt, wtr.z, btr.z));
            ac.w += live * cos_rev(fmaf(dt, wtr.w, btr.w));
        }
        // memb is prescaled x2 -> no epilogue scaling
        u16x4 pm = { f2bf(am.x), f2bf(am.y), f2bf(am.z), f2bf(am.w) };
        u16x4 pc = { f2bf(ac.x), f2bf(ac.y), f2bf(ac.z), f2bf(ac.w) };
        u16x4 pe = { f2bf(ae.x), f2bf(ae.y), f2bf(ae.z), f2bf(ae.w) };
        *reinterpret_cast<u16x4*>(&nf[r][d4])       = pm;
        *reinterpret_cast<u16x4*>(&nf[r][128 + d4]) = pc;
        *reinterpret_cast<u16x4*>(&nf[r][256 + d4]) = pe;
        *reinterpret_cast<u16x4*>(&cat[r][128 + d4]) =
            *reinterpret_cast<const u16x4*>(&memb[(size_t)s_mid[r] * 128 + d4]);  // prescaled
        if (wcache) {
            *reinterpret_cast<f32x4*>(&cache[(size_t)(row0 + r) * 256 + d4]) = ac;
            *reinterpret_cast<f32x4*>(&cache[(size_t)(row0 + r) * 256 + 128 + d4]) = ae;
        }
    }
    __syncthreads();

    const int lane = tid & 63;
    const int wv = tid >> 6;
    const int lo = lane & 15, hi = lane >> 4;

    // ---- GEMM1: s = relu(nf @ W1 + 20*b1) ----
    f32x4 acc[2];
    acc[0] = (f32x4){0.f,0.f,0.f,0.f}; acc[1] = (f32x4){0.f,0.f,0.f,0.f};
    for (int ks = 0; ks < KS1; ++ks) {
        const short8 a = *reinterpret_cast<const short8*>(&nf[lo][ks * 32 + hi * 8]);
#pragma unroll
        for (int c = 0; c < 2; ++c) {
            const int ct = wv * 2 + c;
            const short8 b = *reinterpret_cast<const short8*>(
                &wf1[(((size_t)ct * KS1 + ks) * 64 + lane) * 8]);
            acc[c] = __builtin_amdgcn_mfma_f32_16x16x32_bf16(a, b, acc[c], 0, 0, 0);
        }
    }
#pragma unroll
    for (int c = 0; c < 2; ++c) {
        const int col = (wv * 2 + c) * 16 + lo;
        const float bv = 20.f * b1l[col];
#pragma unroll
        for (int j = 0; j < 4; ++j) {
            const int r = hi * 4 + j;              // C layout: col=lane&15, row=(lane>>4)*4+j
            cat[r][col] = f2bf(fmaxf(acc[c][j] + bv, 0.f));
        }
    }
    __syncthreads();

    // ---- GEMM2: emb = cat @ W2[0:256] + bias2_eff ----
    acc[0] = (f32x4){0.f,0.f,0.f,0.f}; acc[1] = (f32x4){0.f,0.f,0.f,0.f};
    for (int ks = 0; ks < KS2; ++ks) {
        const short8 a = *reinterpret_cast<const short8*>(&cat[lo][ks * 32 + hi * 8]);
#pragma unroll
        for (int c = 0; c < 2; ++c) {
            const int ct = wv * 2 + c;
            const short8 b = *reinterpret_cast<const short8*>(
                &wf2[(((size_t)ct * KS2 + ks) * 64 + lane) * 8]);
            acc[c] = __builtin_amdgcn_mfma_f32_16x16x32_bf16(a, b, acc[c], 0, 0, 0);
        }
    }
#pragma unroll
    for (int c = 0; c < 2; ++c) {
        const int col = (wv * 2 + c) * 16 + lo;
        const float bv = bias2l[col];
#pragma unroll
        for (int j = 0; j < 4; ++j) {
            const int r = hi * 4 + j;
            emb_all[(size_t)(row0 + r) * 128 + col] = f2bf(acc[c][j] + bv);
        }
    }
}

// ---------------------------------------------------------------------------
// Layer-2 fused MLP: 4 rows/block, wave per row. No edge gathers, no cos:
// cos/edge sums come from cache (bit-identical to layer-1's computation).
// Neighbor embeddings = contiguous embL1 rows; conv mid = raw bf16 copy.
// ---------------------------------------------------------------------------
__global__ __launch_bounds__(256) void mlp_l2(
    const int* __restrict__ nbr1,
    const unsigned short* __restrict__ emb_all,  // bf16 [21504,128] = [conv ; embL1]
    const float* __restrict__ cache,             // f32 [1024,256]
    const unsigned short* __restrict__ wf1,
    const unsigned short* __restrict__ wf2,
    const float* __restrict__ b1l,
    const float* __restrict__ bias2l,
    float* __restrict__ out)
{
    __shared__ alignas(16) unsigned short nf[16][NFPAD];
    __shared__ alignas(16) unsigned short cat[16][CATPAD];
    __shared__ int s_nbr[4][KNBR];

    const int tid = threadIdx.x;
    const int row0 = blockIdx.x * 4;
    const int lane = tid & 63;
    const int wv = tid >> 6;
    const int d2 = lane * 2;

    for (int i = tid; i < 4 * KNBR; i += 256)
        (&s_nbr[0][0])[i] = nbr1[row0 * KNBR + i];
    __syncthreads();

    {
        const int r = wv;
        const int row = row0 + r;
        float am0 = 0.f, am1 = 0.f;
#pragma unroll
        for (int k = 0; k < KNBR; ++k) {
            const int nid = __builtin_amdgcn_readfirstlane(s_nbr[r][k]);
            const u16x2 mu = *reinterpret_cast<const u16x2*>(
                &emb_all[(size_t)(1024 + row * KNBR + k) * 128 + d2]);
            const float m0 = bf2f(mu.x), m1 = bf2f(mu.y);
            am0 += m0; am1 += m1;
            if (nid == 0) { am0 -= m0; am1 -= m1; }
        }
        *reinterpret_cast<u16x2*>(&nf[r][d2]) = (u16x2){ f2bf(am0), f2bf(am1) };
        const f32x2 cc = *reinterpret_cast<const f32x2*>(&cache[(size_t)row * 256 + d2]);
        const f32x2 ce = *reinterpret_cast<const f32x2*>(&cache[(size_t)row * 256 + 128 + d2]);
        *reinterpret_cast<u16x2*>(&nf[r][128 + d2]) = (u16x2){ f2bf(cc.x), f2bf(cc.y) };
        *reinterpret_cast<u16x2*>(&nf[r][256 + d2]) = (u16x2){ f2bf(ce.x), f2bf(ce.y) };
        *reinterpret_cast<u16x2*>(&cat[r][128 + d2]) =
            *reinterpret_cast<const u16x2*>(&emb_all[(size_t)row * 128 + d2]);  // conv
    }
    __syncthreads();

    const int lo = lane & 15, hi = lane >> 4;

    // ---- GEMM1 ----
    f32x4 acc[2];
    acc[0] = (f32x4){0.f,0.f,0.f,0.f}; acc[1] = (f32x4){0.f,0.f,0.f,0.f};
    for (int ks = 0; ks < KS1; ++ks) {
        const short8 a = *reinterpret_cast<const short8*>(&nf[lo][ks * 32 + hi * 8]);
#pragma unroll
        for (int c = 0; c < 2; ++c) {
            const int ct = wv * 2 + c;
            const short8 b = *reinterpret_cast<const short8*>(
                &wf1[(((size_t)ct * KS1 + ks) * 64 + lane) * 8]);
            acc[c] = __builtin_amdgcn_mfma_f32_16x16x32_bf16(a, b, acc[c], 0, 0, 0);
        }
    }
#pragma unroll
    for (int c = 0; c < 2; ++c) {
        const int col = (wv * 2 + c) * 16 + lo;
        const float bv = 20.f * b1l[col];
#pragma unroll
        for (int j = 0; j < 4; ++j) {
            const int r = hi * 4 + j;
            if (r < 4) cat[r][col] = f2bf(fmaxf(acc[c][j] + bv, 0.f));
        }
    }
    __syncthreads();

    // ---- GEMM2 -> out (f32) ----
    acc[0] = (f32x4){0.f,0.f,0.f,0.f}; acc[1] = (f32x4){0.f,0.f,0.f,0.f};
    for (int ks = 0; ks < KS2; ++ks) {
        const short8 a = *reinterpret_cast<const short8*>(&cat[lo][ks * 32 + hi * 8]);
#pragma unroll
        for (int c = 0; c < 2; ++c) {
            const int ct = wv * 2 + c;
            const short8 b = *reinterpret_cast<const short8*>(
                &wf2[(((size_t)ct * KS2 + ks) * 64 + lane) * 8]);
            acc[c] = __builtin_amdgcn_mfma_f32_16x16x32_bf16(a, b, acc[c], 0, 0, 0);
        }
    }
#pragma unroll
    for (int c = 0; c < 2; ++c) {
        const int col = (wv * 2 + c) * 16 + lo;
        const float bv = bias2l[col];
#pragma unroll
        for (int j = 0; j < 4; ++j) {
            const int r = hi * 4 + j;
            if (r < 4) out[(size_t)(row0 + r) * 128 + col] = acc[c][j] + bv;
        }
    }
}

// ---------------------------------------------------------------------------
extern "C" void kernel_launch(void* const* d_in, const int* in_sizes, int n_in,
                              void* d_out, int out_size, void* d_ws, size_t ws_size,
                              hipStream_t stream) {
    const float* memory        = (const float*)d_in[0];
    const float* edge_features = (const float*)d_in[1];
    const float* timestamps    = (const float*)d_in[2];
    const float* time_w        = (const float*)d_in[3];
    const float* time_b        = (const float*)d_in[4];
    const float* W1            = (const float*)d_in[5];
    const float* b1            = (const float*)d_in[6];
    const float* W2            = (const float*)d_in[7];
    const float* b2            = (const float*)d_in[8];
    const int*   source_nodes  = (const int*)d_in[9];
    const int*   nbr1          = (const int*)d_in[10];
    const int*   eidx1         = (const int*)d_in[11];
    const float* etime1        = (const float*)d_in[12];
    const int*   nbr2          = (const int*)d_in[13];
    const int*   eidx2         = (const int*)d_in[14];
    const float* etime2        = (const float*)d_in[15];

    const int N = 1024;
    const int NROWS = N + N * KNBR;  // 21504

    // ws: memb bf16 [12.8M] | emb_all bf16 [21504*128] | cache f32 [1024*256]
    //     | bias2_eff f32 [256] | wf1 u16 | wf2 u16
    unsigned short* memb = (unsigned short*)d_ws;
    unsigned short* emb_all = memb + NMEM_ELEMS;
    float* cache = (float*)(emb_all + (size_t)NROWS * 128);
    float* bias2_eff = cache + (size_t)1024 * 256;
    unsigned short* wf1 = (unsigned short*)(bias2_eff + 256);
    unsigned short* wf2 = wf1 + 2 * WF1_PER_LAYER;

    setup_kernel<<<641 + NMEM_ELEMS / 4 / 256, 256, 0, stream>>>(
        memory, W1, W2, b2, time_b, wf1, wf2, bias2_eff, memb);

    mlp_l1<<<NROWS / 16, 256, 0, stream>>>(
        memb, edge_features, timestamps, time_w, time_b, source_nodes,
        nbr1, eidx1, etime1, nbr2, eidx2, etime2,
        wf1, wf2, b1, bias2_eff, cache, emb_all);

    mlp_l2<<<N / 4, 256, 0, stream>>>(
        nbr1, emb_all, cache,
        wf1 + WF1_PER_LAYER, wf2 + WF2_PER_LAYER,
        b1 + 128, bias2_eff + 128, (float*)d_out);
}

// Round 11
// 120.399 us; speedup vs baseline: 1.0837x; 1.0837x over previous
//
#include <hip/hip_runtime.h>
#include <hip/hip_bf16.h>
#include <math.h>

#define KNBR 20
#define NFK 384
#define NFPAD 392     // bf16 pad -> row stride 784B
#define CATPAD 264
#define KS1 12        // 384/32 k-steps
#define KS2 8         // 256/32 k-steps ("ones" block folded into bias2_eff)
#define WF1_PER_LAYER (8 * KS1 * 64 * 8)   // 49152
#define WF2_PER_LAYER (8 * KS2 * 64 * 8)   // 32768
#define INV2PI 0.15915494309189535f
#define NMEM_ELEMS 12800000                // 100000*128

typedef __attribute__((ext_vector_type(8))) short short8;
typedef __attribute__((ext_vector_type(4))) float f32x4;
typedef __attribute__((ext_vector_type(2))) float f32x2;
typedef __attribute__((ext_vector_type(4))) unsigned short u16x4;
typedef __attribute__((ext_vector_type(2))) unsigned short u16x2;

__device__ __forceinline__ unsigned short f2bf(float f) {
    unsigned u = __float_as_uint(f);
    unsigned r = (u + 0x7FFFu + ((u >> 16) & 1u)) >> 16;  // RNE
    return (unsigned short)r;
}
__device__ __forceinline__ float bf2f(unsigned short u) {
    return __uint_as_float((unsigned)u << 16);
}
__device__ __forceinline__ float fract_(float x) {
#if __has_builtin(__builtin_amdgcn_fractf)
    return __builtin_amdgcn_fractf(x);
#else
    return x - floorf(x);
#endif
}
__device__ __forceinline__ float cos_rev(float rev) {  // cos(2*pi*rev)
#if __has_builtin(__builtin_amdgcn_cosf)
    return __builtin_amdgcn_cosf(fract_(rev));
#else
    float o, r = fract_(rev);
    asm("v_cos_f32 %0, %1" : "=v"(o) : "v"(r));
    return o;
#endif
}
__device__ __forceinline__ f32x4 ldnt4(const float* p) {  // non-temporal 16B load
    return __builtin_nontemporal_load(reinterpret_cast<const f32x4*>(p));
}

// ---------------------------------------------------------------------------
// One-time setup: weight repack to MFMA B-frag order (bf16), ones-bias fold,
// memory-table f32 -> bf16 conversion PRESCALED x2 (node_feat = 2*memory).
// Conversion: nt READ (read-once), REGULAR store (keep memb cache-resident).
// Consumer reads: wf[(((ct*KS + ks)*64 + lane)*8 + j]
//   k = ks*32 + (lane>>4)*8 + j, col = ct*16 + (lane&15)
// ---------------------------------------------------------------------------
__global__ __launch_bounds__(256) void setup_kernel(
    const float* __restrict__ memory,
    const float* __restrict__ W1, const float* __restrict__ W2,
    const float* __restrict__ b2, const float* __restrict__ time_b,
    unsigned short* __restrict__ wf1, unsigned short* __restrict__ wf2,
    float* __restrict__ bias2_eff, unsigned short* __restrict__ memb)
{
    const int id = blockIdx.x * 256 + threadIdx.x;
    const int N1 = 2 * WF1_PER_LAYER;
    const int N2 = 2 * WF2_PER_LAYER;
    if (id < N1) {
        const int layer = id / WF1_PER_LAYER;
        const int idl = id % WF1_PER_LAYER;
        const int ct = idl / (KS1 * 512);
        const int ks = (idl / 512) % KS1;
        const int l = (idl >> 3) & 63;
        const int j = idl & 7;
        const int k = ks * 32 + (l >> 4) * 8 + j;
        const int col = ct * 16 + (l & 15);
        wf1[id] = f2bf(W1[(size_t)layer * NFK * 128 + k * 128 + col]);
    } else if (id < N1 + N2) {
        const int id2 = id - N1;
        const int layer = id2 / WF2_PER_LAYER;
        const int idl = id2 % WF2_PER_LAYER;
        const int ct = idl / (KS2 * 512);
        const int ks = (idl / 512) % KS2;
        const int l = (idl >> 3) & 63;
        const int j = idl & 7;
        const int k = ks * 32 + (l >> 4) * 8 + j;
        const int col = ct * 16 + (l & 15);
        wf2[id2] = f2bf(W2[(size_t)layer * NFK * 128 + k * 128 + col]);
    } else if (id < N1 + N2 + 256) {
        const int id3 = id - N1 - N2;
        const int layer = id3 / 128, col = id3 % 128;
        float s = b2[layer * 128 + col];
        for (int f = 0; f < 128; ++f)
            s += cosf(time_b[f]) * W2[(size_t)layer * NFK * 128 + (256 + f) * 128 + col];
        bias2_eff[id3] = s;
    } else {
        // prescaled x2 conversion (exact: 2*bf16(v) == bf16(2v))
        const size_t cid = (size_t)(id - (N1 + N2 + 256)) * 4;
        const f32x4 v = __builtin_nontemporal_load(
            reinterpret_cast<const f32x4*>(&memory[cid]));
        u16x4 o = { f2bf(2.f*v.x), f2bf(2.f*v.y), f2bf(2.f*v.z), f2bf(2.f*v.w) };
        *reinterpret_cast<u16x4*>(&memb[cid]) = o;   // cacheable store
    }
}

// ---------------------------------------------------------------------------
// Layer-1 fused MLP: 256 threads (4 waves), 16 rows/block.
// r11 single-variable probe: __launch_bounds__(256,3) (~170 VGPR ceiling,
// 3 blocks/CU = 12 waves/CU) with the FULL k=20 unroll kept (r10's unroll
// cap is reverted -- in-flight loads per wave stay at r9's level).
// Staging: half-wave hw (32 lanes) owns 2 rows; 4 dims/lane.
// memb gathers: bf16 8B/lane, cacheable. edge gathers: f32 16B/lane, nt.
// Writes f32 cos/edge sums for rows<1024 into cache (reused by layer-2).
// ---------------------------------------------------------------------------
__global__ __launch_bounds__(256, 3) void mlp_l1(
    const unsigned short* __restrict__ memb,   // bf16 [100000,128], prescaled x2
    const float* __restrict__ edge_features,
    const float* __restrict__ timestamps,
    const float* __restrict__ time_w,
    const float* __restrict__ time_b,
    const int* __restrict__ source_nodes,
    const int* __restrict__ nbr1, const int* __restrict__ eidx1, const float* __restrict__ etime1,
    const int* __restrict__ nbr2, const int* __restrict__ eidx2, const float* __restrict__ etime2,
    const unsigned short* __restrict__ wf1,
    const unsigned short* __restrict__ wf2,
    const float* __restrict__ b1l,
    const float* __restrict__ bias2l,
    float* __restrict__ cache,                 // f32 [1024,256]: [cos_sum | edge_sum]
    unsigned short* __restrict__ emb_all)      // bf16 [21504,128] out
{
    __shared__ alignas(16) unsigned short nf[16][NFPAD];
    __shared__ alignas(16) unsigned short cat[16][CATPAD];
    __shared__ int   s_nbr[16][KNBR];
    __shared__ int   s_eix[16][KNBR];
    __shared__ float s_etm[16][KNBR];
    __shared__ float s_ts[16];
    __shared__ int   s_mid[16];

    const int tid = threadIdx.x;
    const int row0 = blockIdx.x * 16;
    const int l32 = tid & 31;
    const int d4 = l32 * 4;
    const int hw = tid >> 5;

    // --- block-cooperative index staging ---
    const int* nbr_src; const int* eix_src; const float* etm_src;
    if (row0 < 1024) {
        nbr_src = nbr1 + row0 * KNBR; eix_src = eidx1 + row0 * KNBR; etm_src = etime1 + row0 * KNBR;
    } else {
        const int i0 = row0 - 1024;
        nbr_src = nbr2 + i0 * KNBR; eix_src = eidx2 + i0 * KNBR; etm_src = etime2 + i0 * KNBR;
    }
    for (int i = tid; i < 16 * KNBR; i += 256) {
        (&s_nbr[0][0])[i] = nbr_src[i];
        (&s_eix[0][0])[i] = eix_src[i];
        (&s_etm[0][0])[i] = etm_src[i];
    }
    if (tid < 16) {
        const int row = row0 + tid;
        float ts; int mid;
        if (row0 < 1024) { ts = timestamps[row]; mid = source_nodes[row]; }
        else { const int i = row - 1024; ts = timestamps[i / KNBR]; mid = nbr1[i]; }
        s_ts[tid] = ts;
        s_mid[tid] = mid;
    }
    __syncthreads();

    const f32x4 twv = *reinterpret_cast<const f32x4*>(&time_w[d4]);
    const f32x4 tbv = *reinterpret_cast<const f32x4*>(&time_b[d4]);
    const f32x4 wtr = twv * INV2PI;
    const f32x4 btr = tbv * INV2PI;
    const bool wcache = (row0 < 1024);

#pragma unroll
    for (int ri = 0; ri < 2; ++ri) {
        const int r = hw * 2 + ri;
        const float ts = s_ts[r];
        f32x4 am = {0,0,0,0}, ac = {0,0,0,0}, ae = {0,0,0,0};
#pragma unroll
        for (int k = 0; k < KNBR; ++k) {
            const int nid = s_nbr[r][k];
            const int eid = s_eix[r][k];
            const float dt = ts - s_etm[r][k];
            const float live = (nid != 0) ? 1.f : 0.f;
            const u16x4 mu = *reinterpret_cast<const u16x4*>(&memb[(size_t)nid * 128 + d4]);
            const f32x4 ev = ldnt4(&edge_features[(size_t)eid * 128 + d4]);
            am.x += live * bf2f(mu.x); am.y += live * bf2f(mu.y);
            am.z += live * bf2f(mu.z); am.w += live * bf2f(mu.w);
            ae += live * ev;
            ac.x += live * cos_rev(fmaf(dt, wtr.x, btr.x));
            ac.y += live * cos_rev(fmaf(dt, wtr.y, btr.y));
            ac.z += live * cos_rev(fmaf(dt, wtr.z, btr.z));
            ac.w += live * cos_rev(fmaf(dt, wtr.w, btr.w));
        }
        // memb is prescaled x2 -> no epilogue scaling
        u16x4 pm = { f2bf(am.x), f2bf(am.y), f2bf(am.z), f2bf(am.w) };
        u16x4 pc = { f2bf(ac.x), f2bf(ac.y), f2bf(ac.z), f2bf(ac.w) };
        u16x4 pe = { f2bf(ae.x), f2bf(ae.y), f2bf(ae.z), f2bf(ae.w) };
        *reinterpret_cast<u16x4*>(&nf[r][d4])       = pm;
        *reinterpret_cast<u16x4*>(&nf[r][128 + d4]) = pc;
        *reinterpret_cast<u16x4*>(&nf[r][256 + d4]) = pe;
        *reinterpret_cast<u16x4*>(&cat[r][128 + d4]) =
            *reinterpret_cast<const u16x4*>(&memb[(size_t)s_mid[r] * 128 + d4]);  // prescaled
        if (wcache) {
            *reinterpret_cast<f32x4*>(&cache[(size_t)(row0 + r) * 256 + d4]) = ac;
            *reinterpret_cast<f32x4*>(&cache[(size_t)(row0 + r) * 256 + 128 + d4]) = ae;
        }
    }
    __syncthreads();

    const int lane = tid & 63;
    const int wv = tid >> 6;
    const int lo = lane & 15, hi = lane >> 4;

    // ---- GEMM1: s = relu(nf @ W1 + 20*b1) ----
    f32x4 acc[2];
    acc[0] = (f32x4){0.f,0.f,0.f,0.f}; acc[1] = (f32x4){0.f,0.f,0.f,0.f};
    for (int ks = 0; ks < KS1; ++ks) {
        const short8 a = *reinterpret_cast<const short8*>(&nf[lo][ks * 32 + hi * 8]);
#pragma unroll
        for (int c = 0; c < 2; ++c) {
            const int ct = wv * 2 + c;
            const short8 b = *reinterpret_cast<const short8*>(
                &wf1[(((size_t)ct * KS1 + ks) * 64 + lane) * 8]);
            acc[c] = __builtin_amdgcn_mfma_f32_16x16x32_bf16(a, b, acc[c], 0, 0, 0);
        }
    }
#pragma unroll
    for (int c = 0; c < 2; ++c) {
        const int col = (wv * 2 + c) * 16 + lo;
        const float bv = 20.f * b1l[col];
#pragma unroll
        for (int j = 0; j < 4; ++j) {
            const int r = hi * 4 + j;              // C layout: col=lane&15, row=(lane>>4)*4+j
            cat[r][col] = f2bf(fmaxf(acc[c][j] + bv, 0.f));
        }
    }
    __syncthreads();

    // ---- GEMM2: emb = cat @ W2[0:256] + bias2_eff ----
    acc[0] = (f32x4){0.f,0.f,0.f,0.f}; acc[1] = (f32x4){0.f,0.f,0.f,0.f};
    for (int ks = 0; ks < KS2; ++ks) {
        const short8 a = *reinterpret_cast<const short8*>(&cat[lo][ks * 32 + hi * 8]);
#pragma unroll
        for (int c = 0; c < 2; ++c) {
            const int ct = wv * 2 + c;
            const short8 b = *reinterpret_cast<const short8*>(
                &wf2[(((size_t)ct * KS2 + ks) * 64 + lane) * 8]);
            acc[c] = __builtin_amdgcn_mfma_f32_16x16x32_bf16(a, b, acc[c], 0, 0, 0);
        }
    }
#pragma unroll
    for (int c = 0; c < 2; ++c) {
        const int col = (wv * 2 + c) * 16 + lo;
        const float bv = bias2l[col];
#pragma unroll
        for (int j = 0; j < 4; ++j) {
            const int r = hi * 4 + j;
            emb_all[(size_t)(row0 + r) * 128 + col] = f2bf(acc[c][j] + bv);
        }
    }
}

// ---------------------------------------------------------------------------
// Layer-2 fused MLP: 4 rows/block, wave per row. No edge gathers, no cos:
// cos/edge sums come from cache (bit-identical to layer-1's computation).
// Neighbor embeddings = contiguous embL1 rows; conv mid = raw bf16 copy.
// ---------------------------------------------------------------------------
__global__ __launch_bounds__(256) void mlp_l2(
    const int* __restrict__ nbr1,
    const unsigned short* __restrict__ emb_all,  // bf16 [21504,128] = [conv ; embL1]
    const float* __restrict__ cache,             // f32 [1024,256]
    const unsigned short* __restrict__ wf1,
    const unsigned short* __restrict__ wf2,
    const float* __restrict__ b1l,
    const float* __restrict__ bias2l,
    float* __restrict__ out)
{
    __shared__ alignas(16) unsigned short nf[16][NFPAD];
    __shared__ alignas(16) unsigned short cat[16][CATPAD];
    __shared__ int s_nbr[4][KNBR];

    const int tid = threadIdx.x;
    const int row0 = blockIdx.x * 4;
    const int lane = tid & 63;
    const int wv = tid >> 6;
    const int d2 = lane * 2;

    for (int i = tid; i < 4 * KNBR; i += 256)
        (&s_nbr[0][0])[i] = nbr1[row0 * KNBR + i];
    __syncthreads();

    {
        const int r = wv;
        const int row = row0 + r;
        float am0 = 0.f, am1 = 0.f;
#pragma unroll
        for (int k = 0; k < KNBR; ++k) {
            const int nid = __builtin_amdgcn_readfirstlane(s_nbr[r][k]);
            const u16x2 mu = *reinterpret_cast<const u16x2*>(
                &emb_all[(size_t)(1024 + row * KNBR + k) * 128 + d2]);
            const float m0 = bf2f(mu.x), m1 = bf2f(mu.y);
            am0 += m0; am1 += m1;
            if (nid == 0) { am0 -= m0; am1 -= m1; }
        }
        *reinterpret_cast<u16x2*>(&nf[r][d2]) = (u16x2){ f2bf(am0), f2bf(am1) };
        const f32x2 cc = *reinterpret_cast<const f32x2*>(&cache[(size_t)row * 256 + d2]);
        const f32x2 ce = *reinterpret_cast<const f32x2*>(&cache[(size_t)row * 256 + 128 + d2]);
        *reinterpret_cast<u16x2*>(&nf[r][128 + d2]) = (u16x2){ f2bf(cc.x), f2bf(cc.y) };
        *reinterpret_cast<u16x2*>(&nf[r][256 + d2]) = (u16x2){ f2bf(ce.x), f2bf(ce.y) };
        *reinterpret_cast<u16x2*>(&cat[r][128 + d2]) =
            *reinterpret_cast<const u16x2*>(&emb_all[(size_t)row * 128 + d2]);  // conv
    }
    __syncthreads();

    const int lo = lane & 15, hi = lane >> 4;

    // ---- GEMM1 ----
    f32x4 acc[2];
    acc[0] = (f32x4){0.f,0.f,0.f,0.f}; acc[1] = (f32x4){0.f,0.f,0.f,0.f};
    for (int ks = 0; ks < KS1; ++ks) {
        const short8 a = *reinterpret_cast<const short8*>(&nf[lo][ks * 32 + hi * 8]);
#pragma unroll
        for (int c = 0; c < 2; ++c) {
            const int ct = wv * 2 + c;
            const short8 b = *reinterpret_cast<const short8*>(
                &wf1[(((size_t)ct * KS1 + ks) * 64 + lane) * 8]);
            acc[c] = __builtin_amdgcn_mfma_f32_16x16x32_bf16(a, b, acc[c], 0, 0, 0);
        }
    }
#pragma unroll
    for (int c = 0; c < 2; ++c) {
        const int col = (wv * 2 + c) * 16 + lo;
        const float bv = 20.f * b1l[col];
#pragma unroll
        for (int j = 0; j < 4; ++j) {
            const int r = hi * 4 + j;
            if (r < 4) cat[r][col] = f2bf(fmaxf(acc[c][j] + bv, 0.f));
        }
    }
    __syncthreads();

    // ---- GEMM2 -> out (f32) ----
    acc[0] = (f32x4){0.f,0.f,0.f,0.f}; acc[1] = (f32x4){0.f,0.f,0.f,0.f};
    for (int ks = 0; ks < KS2; ++ks) {
        const short8 a = *reinterpret_cast<const short8*>(&cat[lo][ks * 32 + hi * 8]);
#pragma unroll
        for (int c = 0; c < 2; ++c) {
            const int ct = wv * 2 + c;
            const short8 b = *reinterpret_cast<const short8*>(
                &wf2[(((size_t)ct * KS2 + ks) * 64 + lane) * 8]);
            acc[c] = __builtin_amdgcn_mfma_f32_16x16x32_bf16(a, b, acc[c], 0, 0, 0);
        }
    }
#pragma unroll
    for (int c = 0; c < 2; ++c) {
        const int col = (wv * 2 + c) * 16 + lo;
        const float bv = bias2l[col];
#pragma unroll
        for (int j = 0; j < 4; ++j) {
            const int r = hi * 4 + j;
            if (r < 4) out[(size_t)(row0 + r) * 128 + col] = acc[c][j] + bv;
        }
    }
}

// ---------------------------------------------------------------------------
extern "C" void kernel_launch(void* const* d_in, const int* in_sizes, int n_in,
                              void* d_out, int out_size, void* d_ws, size_t ws_size,
                              hipStream_t stream) {
    const float* memory        = (const float*)d_in[0];
    const float* edge_features = (const float*)d_in[1];
    const float* timestamps    = (const float*)d_in[2];
    const float* time_w        = (const float*)d_in[3];
    const float* time_b        = (const float*)d_in[4];
    const float* W1            = (const float*)d_in[5];
    const float* b1            = (const float*)d_in[6];
    const float* W2            = (const float*)d_in[7];
    const float* b2            = (const float*)d_in[8];
    const int*   source_nodes  = (const int*)d_in[9];
    const int*   nbr1          = (const int*)d_in[10];
    const int*   eidx1         = (const int*)d_in[11];
    const float* etime1        = (const float*)d_in[12];
    const int*   nbr2          = (const int*)d_in[13];
    const int*   eidx2         = (const int*)d_in[14];
    const float* etime2        = (const float*)d_in[15];

    const int N = 1024;
    const int NROWS = N + N * KNBR;  // 21504

    // ws: memb bf16 [12.8M] | emb_all bf16 [21504*128] | cache f32 [1024*256]
    //     | bias2_eff f32 [256] | wf1 u16 | wf2 u16
    unsigned short* memb = (unsigned short*)d_ws;
    unsigned short* emb_all = memb + NMEM_ELEMS;
    float* cache = (float*)(emb_all + (size_t)NROWS * 128);
    float* bias2_eff = cache + (size_t)1024 * 256;
    unsigned short* wf1 = (unsigned short*)(bias2_eff + 256);
    unsigned short* wf2 = wf1 + 2 * WF1_PER_LAYER;

    setup_kernel<<<641 + NMEM_ELEMS / 4 / 256, 256, 0, stream>>>(
        memory, W1, W2, b2, time_b, wf1, wf2, bias2_eff, memb);

    mlp_l1<<<NROWS / 16, 256, 0, stream>>>(
        memb, edge_features, timestamps, time_w, time_b, source_nodes,
        nbr1, eidx1, etime1, nbr2, eidx2, etime2,
        wf1, wf2, b1, bias2_eff, cache, emb_all);

    mlp_l2<<<N / 4, 256, 0, stream>>>(
        nbr1, emb_all, cache,
        wf1 + WF1_PER_LAYER, wf2 + WF2_PER_LAYER,
        b1 + 128, bias2_eff + 128, (float*)d_out);
}